// Round 2
// baseline (4779.775 us; speedup 1.0000x reference)
//
#include <hip/hip_runtime.h>
#include <hip/hip_bf16.h>

// DecoderRNNsearch on MI355X — precision-hardened version.
// The recurrence amplifies per-step noise by ~700x over 64 steps (sharp
// softmax attention), so every sequential-path operand is effective-fp32:
//   ctxW  = ctx@Wa^T   : split-bf16 3-pass GEMM, fp32 out
//   ctxWc = ctx@Wc^T   : split-bf16 3-pass GEMM, fp32 out  (read fp32 in loop)
//   gh    = Whh@h      : split-bf16 3-pass MFMA in-step (W and h hi/lo planes)
//   gxe   = emb@We^T+b : single bf16 GEMM (|gxe|~3e-3, rounding negligible)
// All 3H-dim data row-permuted j' = 3u+g (u=hidden unit, g=r/z/n gate).

using short8 = __attribute__((ext_vector_type(8))) short;
using f32x4  = __attribute__((ext_vector_type(4))) float;

#define FLAG_ACC 1
#define FLAG_BF  2

__device__ __forceinline__ void gld16(const void* g, void* l) {
  __builtin_amdgcn_global_load_lds(
      (const __attribute__((address_space(1))) unsigned int*)g,
      (__attribute__((address_space(3))) unsigned int*)l, 16, 0, 0);
}

__device__ __forceinline__ short bf16s(float v) {
  __hip_bfloat16 h = __float2bfloat16(v);
  return *reinterpret_cast<short*>(&h);
}

// ---------------- conversion / prep kernels ----------------

__global__ __launch_bounds__(256) void split_bf16_kernel(
    const float* __restrict__ x, __hip_bfloat16* __restrict__ hi,
    __hip_bfloat16* __restrict__ lo, int n)
{
  int i = blockIdx.x * blockDim.x + threadIdx.x;
  int stride = gridDim.x * blockDim.x;
  for (; i < n; i += stride) {
    float v = x[i];
    __hip_bfloat16 h = __float2bfloat16(v);
    hi[i] = h;
    lo[i] = __float2bfloat16(v - __bfloat162float(h));
  }
}

// permute rows j' = 3u+g  <-  source row g*1024+u ; split to bf16 hi/lo
__global__ __launch_bounds__(256) void prep_weights(
    const float* __restrict__ Wih, const float* __restrict__ Whh,
    const float* __restrict__ bih, const float* __restrict__ bhh,
    __hip_bfloat16* __restrict__ WcH, __hip_bfloat16* __restrict__ WcL,
    __hip_bfloat16* __restrict__ We,
    __hip_bfloat16* __restrict__ WhH, __hip_bfloat16* __restrict__ WhL,
    float* __restrict__ bihp, float* __restrict__ bhhp)
{
  const int jp = blockIdx.x;           // 0..3071
  const int u = jp / 3, g = jp - 3 * u;
  const int src = g * 1024 + u;
  for (int c = threadIdx.x; c < 2048; c += 256) {
    float v = Wih[(size_t)src * 2560 + 512 + c];
    __hip_bfloat16 h = __float2bfloat16(v);
    WcH[(size_t)jp * 2048 + c] = h;
    WcL[(size_t)jp * 2048 + c] = __float2bfloat16(v - __bfloat162float(h));
  }
  for (int c = threadIdx.x; c < 512; c += 256)
    We[(size_t)jp * 512 + c] = __float2bfloat16(Wih[(size_t)src * 2560 + c]);
  for (int c = threadIdx.x; c < 1024; c += 256) {
    float v = Whh[(size_t)src * 1024 + c];
    __hip_bfloat16 h = __float2bfloat16(v);
    WhH[(size_t)jp * 1024 + c] = h;
    WhL[(size_t)jp * 1024 + c] = __float2bfloat16(v - __bfloat162float(h));
  }
  if (threadIdx.x == 0) { bihp[jp] = bih[src]; bhhp[jp] = bhh[src]; }
}

__global__ __launch_bounds__(256) void emb_gather(
    const int* __restrict__ tgt, const float* __restrict__ table,
    __hip_bfloat16* __restrict__ outb)
{
  const int row = blockIdx.x;          // b*64+t, 0..4095
  const int v = tgt[row];
  for (int c = threadIdx.x; c < 512; c += 256)
    outb[(size_t)row * 512 + c] = __float2bfloat16(table[(size_t)v * 512 + c]);
}

__global__ __launch_bounds__(256) void h0_init(
    const float* __restrict__ h0, float* __restrict__ hf,
    __hip_bfloat16* __restrict__ hhi, __hip_bfloat16* __restrict__ hlo)
{
  const int i = blockIdx.x * 256 + threadIdx.x;   // grid 256 -> 65536
  float v = h0[i];
  hf[i] = v;
  __hip_bfloat16 h = __float2bfloat16(v);
  hhi[i] = h;
  hlo[i] = __float2bfloat16(v - __bfloat162float(h));
}

// ---------------- generic bf16 GEMM  C[M,N] = A[M,K] @ B[N,K]^T ----------------
// 128x128 block tile, 4 waves each 64x64, BK=32, global_load_lds staging (m97 recipe).
// flags: FLAG_ACC -> C += , FLAG_BF -> write bf16 to Cb else fp32 to Cf. bias added per-n.

__global__ __launch_bounds__(256) void gemm_bt(
    const short* __restrict__ A, const short* __restrict__ B,
    float* __restrict__ Cf, __hip_bfloat16* __restrict__ Cb,
    const float* __restrict__ bias, int M, int N, int K, int flags)
{
  __shared__ __align__(16) short As[128 * 32];
  __shared__ __align__(16) short Bs[128 * 32];
  const int tid = threadIdx.x, lane = tid & 63, w = tid >> 6;
  const int m0 = blockIdx.y * 128, n0 = blockIdx.x * 128;
  const int wm = (w >> 1) * 64, wn = (w & 1) * 64;
  const int srow = lane >> 2, scol = (lane & 3) * 8;   // staging: 16 rows x 64B per 1KB chunk
  f32x4 zero = {0.f, 0.f, 0.f, 0.f};
  f32x4 acc[4][4];
#pragma unroll
  for (int i = 0; i < 4; ++i)
#pragma unroll
    for (int j = 0; j < 4; ++j) acc[i][j] = zero;

  for (int k0 = 0; k0 < K; k0 += 32) {
    __syncthreads();
#pragma unroll
    for (int s = 0; s < 2; ++s) {
      const int chunk = w * 2 + s;               // 0..7, wave-uniform
      const int r = chunk * 16 + srow;           // 0..127
      gld16(A + (size_t)(m0 + r) * K + k0 + scol, As + chunk * 512);
      gld16(B + (size_t)(n0 + r) * K + k0 + scol, Bs + chunk * 512);
    }
    __syncthreads();
    const int fm = lane & 15, fq = lane >> 4;
    short8 af[4], bq[4];
#pragma unroll
    for (int i = 0; i < 4; ++i)
      af[i] = *(const short8*)(As + (wm + i * 16 + fm) * 32 + fq * 8);
#pragma unroll
    for (int j = 0; j < 4; ++j)
      bq[j] = *(const short8*)(Bs + (wn + j * 16 + fm) * 32 + fq * 8);
#pragma unroll
    for (int i = 0; i < 4; ++i)
#pragma unroll
      for (int j = 0; j < 4; ++j)
        acc[i][j] = __builtin_amdgcn_mfma_f32_16x16x32_bf16(af[i], bq[j], acc[i][j], 0, 0, 0);
  }

  // D layout: col(n)=lane&15, row(m)=(lane>>4)*4+reg
  const int cn = lane & 15, cq = (lane >> 4) * 4;
#pragma unroll
  for (int i = 0; i < 4; ++i) {
#pragma unroll
    for (int j = 0; j < 4; ++j) {
#pragma unroll
      for (int r = 0; r < 4; ++r) {
        const int m = m0 + wm + i * 16 + cq + r;
        const int n = n0 + wn + j * 16 + cn;
        float v = acc[i][j][r];
        if (flags & FLAG_ACC) v += Cf[(size_t)m * N + n];
        if (bias) v += bias[n];
        if (flags & FLAG_BF) Cb[(size_t)m * N + n] = __float2bfloat16(v);
        else                 Cf[(size_t)m * N + n] = v;
      }
    }
  }
}

// ---------------- per-step kernels ----------------

// one block per batch: scores (fp32, K=1024) -> masked softmax -> attn[b,0..63]
__global__ __launch_bounds__(256) void attn_kernel(
    const float* __restrict__ hf, const float* __restrict__ ctxW,
    const int* __restrict__ lens, float* __restrict__ attn)
{
  __shared__ float hs[1024];
  __shared__ float part[256];
  const int b = blockIdx.x, tid = threadIdx.x;
  ((float4*)hs)[tid] = ((const float4*)(hf + b * 1024))[tid];
  __syncthreads();
  const int l = tid >> 2, q = tid & 3;
  const float4* row = (const float4*)(ctxW + ((size_t)(b * 64 + l)) * 1024 + q * 256);
  const float4* hh = (const float4*)(hs + q * 256);
  float s = 0.f;
#pragma unroll 8
  for (int i = 0; i < 64; ++i) {
    float4 a = row[i], c = hh[i];
    s += a.x * c.x + a.y * c.y + a.z * c.z + a.w * c.w;
  }
  part[tid] = s;
  __syncthreads();
  if (tid < 64) {   // exactly wave 0
    float sc = part[tid * 4] + part[tid * 4 + 1] + part[tid * 4 + 2] + part[tid * 4 + 3];
    if (tid >= lens[b]) sc = -1e9f;
    float m = sc;
#pragma unroll
    for (int off = 32; off > 0; off >>= 1) m = fmaxf(m, __shfl_xor(m, off));
    float e = __expf(sc - m);
    float sum = e;
#pragma unroll
    for (int off = 32; off > 0; off >>= 1) sum += __shfl_xor(sum, off);
    attn[b * 64 + tid] = e / sum;
  }
}

// one block per 16 hidden units (48 permuted rows). 4 waves:
// gh = h @ Whh_slice^T via split-bf16 3-pass MFMA (effective fp32),
// then gx_c (K=64 fp32 contraction with attn over fp32 ctxWc) + gates.
__global__ __launch_bounds__(256) void step_kernel(
    const short* __restrict__ hhi_in, const short* __restrict__ hlo_in,
    short* __restrict__ hhi_out, short* __restrict__ hlo_out,
    float* __restrict__ hf, const float* __restrict__ attn,
    const short* __restrict__ WhH, const short* __restrict__ WhL,
    const float* __restrict__ ctxWc,
    const __hip_bfloat16* __restrict__ gxe,
    const float* __restrict__ bhhp,
    float* __restrict__ out, int t)
{
  __shared__ float attns[64 * 64];
  __shared__ float ghs[48 * 68];   // [j_local][batch], padded stride 68
  const int tid = threadIdx.x, lane = tid & 63, w = tid >> 6;
  const int j0 = blockIdx.x * 48;

  for (int i = tid; i < 64 * 64; i += 256) attns[i] = attn[i];

  const int fm = lane & 15, fq = lane >> 4;
  f32x4 zero = {0.f, 0.f, 0.f, 0.f};
  f32x4 acc0 = zero, acc1 = zero, acc2 = zero;
  const short* ah  = hhi_in + (w * 16 + fm) * 1024 + fq * 8;   // A: batches w*16..+15
  const short* al  = hlo_in + (w * 16 + fm) * 1024 + fq * 8;
  const short* bh0 = WhH + (size_t)(j0 + 0 * 16 + fm) * 1024 + fq * 8;
  const short* bh1 = WhH + (size_t)(j0 + 1 * 16 + fm) * 1024 + fq * 8;
  const short* bh2 = WhH + (size_t)(j0 + 2 * 16 + fm) * 1024 + fq * 8;
  const short* bl0 = WhL + (size_t)(j0 + 0 * 16 + fm) * 1024 + fq * 8;
  const short* bl1 = WhL + (size_t)(j0 + 1 * 16 + fm) * 1024 + fq * 8;
  const short* bl2 = WhL + (size_t)(j0 + 2 * 16 + fm) * 1024 + fq * 8;
#pragma unroll 2
  for (int k0 = 0; k0 < 1024; k0 += 32) {
    short8 aH = *(const short8*)(ah + k0);
    short8 aL = *(const short8*)(al + k0);
    short8 b0 = *(const short8*)(bh0 + k0);
    short8 b1 = *(const short8*)(bh1 + k0);
    short8 b2 = *(const short8*)(bh2 + k0);
    short8 c0 = *(const short8*)(bl0 + k0);
    short8 c1 = *(const short8*)(bl1 + k0);
    short8 c2 = *(const short8*)(bl2 + k0);
    acc0 = __builtin_amdgcn_mfma_f32_16x16x32_bf16(aH, b0, acc0, 0, 0, 0);
    acc1 = __builtin_amdgcn_mfma_f32_16x16x32_bf16(aH, b1, acc1, 0, 0, 0);
    acc2 = __builtin_amdgcn_mfma_f32_16x16x32_bf16(aH, b2, acc2, 0, 0, 0);
    acc0 = __builtin_amdgcn_mfma_f32_16x16x32_bf16(aL, b0, acc0, 0, 0, 0);
    acc1 = __builtin_amdgcn_mfma_f32_16x16x32_bf16(aL, b1, acc1, 0, 0, 0);
    acc2 = __builtin_amdgcn_mfma_f32_16x16x32_bf16(aL, b2, acc2, 0, 0, 0);
    acc0 = __builtin_amdgcn_mfma_f32_16x16x32_bf16(aH, c0, acc0, 0, 0, 0);
    acc1 = __builtin_amdgcn_mfma_f32_16x16x32_bf16(aH, c1, acc1, 0, 0, 0);
    acc2 = __builtin_amdgcn_mfma_f32_16x16x32_bf16(aH, c2, acc2, 0, 0, 0);
  }
  {
    const int mb = w * 16 + fq * 4;
#pragma unroll
    for (int r = 0; r < 4; ++r) {
      ghs[(0 * 16 + fm) * 68 + mb + r] = acc0[r];
      ghs[(1 * 16 + fm) * 68 + mb + r] = acc1[r];
      ghs[(2 * 16 + fm) * 68 + mb + r] = acc2[r];
    }
  }
  __syncthreads();

  // phase 3: thread -> (b = tid>>2, jg = tid&3), 12 consecutive j' = 4 units
  const int b = tid >> 2, jg = tid & 3;
  float gxc[12];
#pragma unroll
  for (int i = 0; i < 12; ++i) gxc[i] = 0.f;
  const float4* cw = (const float4*)(ctxWc + (size_t)(b * 64) * 3072 + j0 + jg * 12);
#pragma unroll 2
  for (int l = 0; l < 64; ++l) {
    float wl = attns[b * 64 + l];
    const float4* p = cw + (size_t)l * 768;
#pragma unroll
    for (int q4 = 0; q4 < 3; ++q4) {
      float4 v = p[q4];
      gxc[4 * q4 + 0] += wl * v.x;
      gxc[4 * q4 + 1] += wl * v.y;
      gxc[4 * q4 + 2] += wl * v.z;
      gxc[4 * q4 + 3] += wl * v.w;
    }
  }
  const __hip_bfloat16* ge = gxe + (size_t)(b * 64 + t) * 3072 + j0 + jg * 12;
#pragma unroll
  for (int uu = 0; uu < 4; ++uu) {
    const int jl = jg * 12 + uu * 3;
    float gxr = gxc[uu * 3 + 0] + __bfloat162float(ge[uu * 3 + 0]);
    float gxz = gxc[uu * 3 + 1] + __bfloat162float(ge[uu * 3 + 1]);
    float gxn = gxc[uu * 3 + 2] + __bfloat162float(ge[uu * 3 + 2]);
    float ghr = ghs[(jl + 0) * 68 + b] + bhhp[j0 + jl + 0];
    float ghz = ghs[(jl + 1) * 68 + b] + bhhp[j0 + jl + 1];
    float ghn = ghs[(jl + 2) * 68 + b] + bhhp[j0 + jl + 2];
    float rr = 1.f / (1.f + __expf(-(gxr + ghr)));
    float zz = 1.f / (1.f + __expf(-(gxz + ghz)));
    float nn = tanhf(gxn + rr * ghn);
    const int u = j0 / 3 + jg * 4 + uu;
    float hold = hf[b * 1024 + u];
    float hn = (1.f - zz) * nn + zz * hold;
    out[(size_t)(b * 64 + t) * 1024 + u] = hn;
    hf[b * 1024 + u] = hn;
    __hip_bfloat16 hh = __float2bfloat16(hn);
    hhi_out[b * 1024 + u] = *reinterpret_cast<short*>(&hh);
    __hip_bfloat16 hl = __float2bfloat16(hn - __bfloat162float(hh));
    hlo_out[b * 1024 + u] = *reinterpret_cast<short*>(&hl);
    if (t == 63) out[(size_t)64 * 64 * 1024 + b * 1024 + u] = hn;
  }
}

// ---------------- launcher ----------------

extern "C" void kernel_launch(void* const* d_in, const int* in_sizes, int n_in,
                              void* d_out, int out_size, void* d_ws, size_t ws_size,
                              hipStream_t stream)
{
  const int*   tgt  = (const int*)  d_in[0];
  const float* ctx  = (const float*)d_in[1];
  const float* h0   = (const float*)d_in[2];
  const int*   lens = (const int*)  d_in[3];
  const float* embt = (const float*)d_in[4];
  const float* Wa   = (const float*)d_in[5];
  const float* Wih  = (const float*)d_in[6];
  const float* Whh  = (const float*)d_in[7];
  const float* bih  = (const float*)d_in[8];
  const float* bhh  = (const float*)d_in[9];
  float* out = (float*)d_out;

  char* p = (char*)d_ws;
  auto take = [&](size_t bytes) {
    char* q = p;
    p += (bytes + 255) & ~(size_t)255;
    return q;
  };
  // ~180 MB of workspace
  short* ctx_hi = (short*)take((size_t)8388608 * 2);
  short* ctx_lo = (short*)take((size_t)8388608 * 2);
  short* Wa_hi  = (short*)take((size_t)2097152 * 2);
  short* Wa_lo  = (short*)take((size_t)2097152 * 2);
  short* WcH    = (short*)take((size_t)3072 * 2048 * 2);
  short* WcL    = (short*)take((size_t)3072 * 2048 * 2);
  short* We_p   = (short*)take((size_t)3072 * 512 * 2);
  short* WhH    = (short*)take((size_t)3072 * 1024 * 2);
  short* WhL    = (short*)take((size_t)3072 * 1024 * 2);
  float* bih_p  = (float*)take(3072 * 4);
  float* bhh_p  = (float*)take(3072 * 4);
  short* emb_bf = (short*)take((size_t)4096 * 512 * 2);
  float* ctxW   = (float*)take((size_t)4096 * 1024 * 4);
  float* ctxWc  = (float*)take((size_t)4096 * 3072 * 4);
  short* gxe    = (short*)take((size_t)4096 * 3072 * 2);
  float* hf     = (float*)take((size_t)65536 * 4);
  short* hhi0   = (short*)take((size_t)65536 * 2);
  short* hlo0   = (short*)take((size_t)65536 * 2);
  short* hhi1   = (short*)take((size_t)65536 * 2);
  short* hlo1   = (short*)take((size_t)65536 * 2);
  float* attn   = (float*)take((size_t)4096 * 4);

  // prologue: conversions
  split_bf16_kernel<<<2048, 256, 0, stream>>>(ctx, (__hip_bfloat16*)ctx_hi,
                                              (__hip_bfloat16*)ctx_lo, 8388608);
  split_bf16_kernel<<<1024, 256, 0, stream>>>(Wa, (__hip_bfloat16*)Wa_hi,
                                              (__hip_bfloat16*)Wa_lo, 2097152);
  prep_weights<<<3072, 256, 0, stream>>>(Wih, Whh, bih, bhh,
      (__hip_bfloat16*)WcH, (__hip_bfloat16*)WcL, (__hip_bfloat16*)We_p,
      (__hip_bfloat16*)WhH, (__hip_bfloat16*)WhL, bih_p, bhh_p);
  emb_gather<<<4096, 256, 0, stream>>>(tgt, embt, (__hip_bfloat16*)emb_bf);
  h0_init<<<256, 256, 0, stream>>>(h0, hf, (__hip_bfloat16*)hhi0,
                                   (__hip_bfloat16*)hlo0);

  // ctxW = ctx @ Wa^T in split-bf16 (3 accumulating passes -> ~fp32 accuracy)
  gemm_bt<<<dim3(8, 32), 256, 0, stream>>>(ctx_hi, Wa_hi, ctxW, nullptr, nullptr,
                                           4096, 1024, 2048, 0);
  gemm_bt<<<dim3(8, 32), 256, 0, stream>>>(ctx_lo, Wa_hi, ctxW, nullptr, nullptr,
                                           4096, 1024, 2048, FLAG_ACC);
  gemm_bt<<<dim3(8, 32), 256, 0, stream>>>(ctx_hi, Wa_lo, ctxW, nullptr, nullptr,
                                           4096, 1024, 2048, FLAG_ACC);
  // ctxWc = ctx @ Wc_perm^T in split-bf16 (3 passes), fp32 out
  gemm_bt<<<dim3(24, 32), 256, 0, stream>>>(ctx_hi, WcH, ctxWc, nullptr, nullptr,
                                            4096, 3072, 2048, 0);
  gemm_bt<<<dim3(24, 32), 256, 0, stream>>>(ctx_lo, WcH, ctxWc, nullptr, nullptr,
                                            4096, 3072, 2048, FLAG_ACC);
  gemm_bt<<<dim3(24, 32), 256, 0, stream>>>(ctx_hi, WcL, ctxWc, nullptr, nullptr,
                                            4096, 3072, 2048, FLAG_ACC);
  // gxe = emb @ We_perm^T + b_ih (bf16 out; |gxe| ~ 3e-3, rounding negligible)
  gemm_bt<<<dim3(24, 32), 256, 0, stream>>>(emb_bf, We_p, nullptr,
                                            (__hip_bfloat16*)gxe, bih_p,
                                            4096, 3072, 512, FLAG_BF);

  // sequential recurrence
  for (int t = 0; t < 64; ++t) {
    attn_kernel<<<64, 256, 0, stream>>>(hf, ctxW, lens, attn);
    const short* hhi_in = (t & 1) ? hhi1 : hhi0;
    const short* hlo_in = (t & 1) ? hlo1 : hlo0;
    short* hhi_out      = (t & 1) ? hhi0 : hhi1;
    short* hlo_out      = (t & 1) ? hlo0 : hlo1;
    step_kernel<<<64, 256, 0, stream>>>(hhi_in, hlo_in, hhi_out, hlo_out,
        hf, attn, WhH, WhL, ctxWc, (const __hip_bfloat16*)gxe, bhh_p, out, t);
  }
}

// Round 3
// 3581.930 us; speedup vs baseline: 1.3344x; 1.3344x over previous
//
#include <hip/hip_runtime.h>
#include <hip/hip_bf16.h>

// DecoderRNNsearch on MI355X — round 3: loop restructured.
//   kernel A (128 blocks): blocks 0-63 attn (scores fp32 + masked softmax,
//     len-skip), blocks 64-127 gh = Whh@h split-bf16 3-pass MFMA -> ghG fp32.
//     (gh depends only on h, not attn -> same dispatch.)
//   kernel B (256 blocks = 64 j-chunks x 4 b-chunks): per-batch compacted
//     attention list (len-skip + attn<1e-8 skip), fp32 ctxWc contraction,
//     gates, h update. ~12MB/step instead of 50MB with 4x the blocks.
// Prologue: split-bf16 3-pass GEMMs fused into gemm_bt3 (one staging pass).
// All 3H-dim data row-permuted j' = 3u+g (u=hidden unit, g=r/z/n gate).

using short8 = __attribute__((ext_vector_type(8))) short;
using f32x4  = __attribute__((ext_vector_type(4))) float;

#define FLAG_ACC 1
#define FLAG_BF  2

__device__ __forceinline__ void gld16(const void* g, void* l) {
  __builtin_amdgcn_global_load_lds(
      (const __attribute__((address_space(1))) unsigned int*)g,
      (__attribute__((address_space(3))) unsigned int*)l, 16, 0, 0);
}

// ---------------- conversion / prep kernels ----------------

__global__ __launch_bounds__(256) void split_bf16_kernel(
    const float* __restrict__ x, __hip_bfloat16* __restrict__ hi,
    __hip_bfloat16* __restrict__ lo, int n)
{
  int i = blockIdx.x * blockDim.x + threadIdx.x;
  int stride = gridDim.x * blockDim.x;
  for (; i < n; i += stride) {
    float v = x[i];
    __hip_bfloat16 h = __float2bfloat16(v);
    hi[i] = h;
    lo[i] = __float2bfloat16(v - __bfloat162float(h));
  }
}

// permute rows j' = 3u+g  <-  source row g*1024+u ; split to bf16 hi/lo
__global__ __launch_bounds__(256) void prep_weights(
    const float* __restrict__ Wih, const float* __restrict__ Whh,
    const float* __restrict__ bih, const float* __restrict__ bhh,
    __hip_bfloat16* __restrict__ WcH, __hip_bfloat16* __restrict__ WcL,
    __hip_bfloat16* __restrict__ We,
    __hip_bfloat16* __restrict__ WhH, __hip_bfloat16* __restrict__ WhL,
    float* __restrict__ bihp, float* __restrict__ bhhp)
{
  const int jp = blockIdx.x;           // 0..3071
  const int u = jp / 3, g = jp - 3 * u;
  const int src = g * 1024 + u;
  for (int c = threadIdx.x; c < 2048; c += 256) {
    float v = Wih[(size_t)src * 2560 + 512 + c];
    __hip_bfloat16 h = __float2bfloat16(v);
    WcH[(size_t)jp * 2048 + c] = h;
    WcL[(size_t)jp * 2048 + c] = __float2bfloat16(v - __bfloat162float(h));
  }
  for (int c = threadIdx.x; c < 512; c += 256)
    We[(size_t)jp * 512 + c] = __float2bfloat16(Wih[(size_t)src * 2560 + c]);
  for (int c = threadIdx.x; c < 1024; c += 256) {
    float v = Whh[(size_t)src * 1024 + c];
    __hip_bfloat16 h = __float2bfloat16(v);
    WhH[(size_t)jp * 1024 + c] = h;
    WhL[(size_t)jp * 1024 + c] = __float2bfloat16(v - __bfloat162float(h));
  }
  if (threadIdx.x == 0) { bihp[jp] = bih[src]; bhhp[jp] = bhh[src]; }
}

__global__ __launch_bounds__(256) void emb_gather(
    const int* __restrict__ tgt, const float* __restrict__ table,
    __hip_bfloat16* __restrict__ outb)
{
  const int row = blockIdx.x;          // b*64+t, 0..4095
  const int v = tgt[row];
  for (int c = threadIdx.x; c < 512; c += 256)
    outb[(size_t)row * 512 + c] = __float2bfloat16(table[(size_t)v * 512 + c]);
}

__global__ __launch_bounds__(256) void h0_init(
    const float* __restrict__ h0, float* __restrict__ hf,
    __hip_bfloat16* __restrict__ hhi, __hip_bfloat16* __restrict__ hlo)
{
  const int i = blockIdx.x * 256 + threadIdx.x;   // grid 256 -> 65536
  float v = h0[i];
  hf[i] = v;
  __hip_bfloat16 h = __float2bfloat16(v);
  hhi[i] = h;
  hlo[i] = __float2bfloat16(v - __bfloat162float(h));
}

// ---------------- bf16 GEMM  C[M,N] = A[M,K] @ B[N,K]^T (single pass) -------
// 128x128 tile, 4 waves, BK=32, global_load_lds staging. Used for gxe (bf16 out).

__global__ __launch_bounds__(256) void gemm_bt(
    const short* __restrict__ A, const short* __restrict__ B,
    float* __restrict__ Cf, __hip_bfloat16* __restrict__ Cb,
    const float* __restrict__ bias, int M, int N, int K, int flags)
{
  __shared__ __align__(16) short As[128 * 32];
  __shared__ __align__(16) short Bs[128 * 32];
  const int tid = threadIdx.x, lane = tid & 63, w = tid >> 6;
  const int m0 = blockIdx.y * 128, n0 = blockIdx.x * 128;
  const int wm = (w >> 1) * 64, wn = (w & 1) * 64;
  const int srow = lane >> 2, scol = (lane & 3) * 8;
  f32x4 zero = {0.f, 0.f, 0.f, 0.f};
  f32x4 acc[4][4];
#pragma unroll
  for (int i = 0; i < 4; ++i)
#pragma unroll
    for (int j = 0; j < 4; ++j) acc[i][j] = zero;

  for (int k0 = 0; k0 < K; k0 += 32) {
    __syncthreads();
#pragma unroll
    for (int s = 0; s < 2; ++s) {
      const int chunk = w * 2 + s;
      const int r = chunk * 16 + srow;
      gld16(A + (size_t)(m0 + r) * K + k0 + scol, As + chunk * 512);
      gld16(B + (size_t)(n0 + r) * K + k0 + scol, Bs + chunk * 512);
    }
    __syncthreads();
    const int fm = lane & 15, fq = lane >> 4;
    short8 af[4], bq[4];
#pragma unroll
    for (int i = 0; i < 4; ++i)
      af[i] = *(const short8*)(As + (wm + i * 16 + fm) * 32 + fq * 8);
#pragma unroll
    for (int j = 0; j < 4; ++j)
      bq[j] = *(const short8*)(Bs + (wn + j * 16 + fm) * 32 + fq * 8);
#pragma unroll
    for (int i = 0; i < 4; ++i)
#pragma unroll
      for (int j = 0; j < 4; ++j)
        acc[i][j] = __builtin_amdgcn_mfma_f32_16x16x32_bf16(af[i], bq[j], acc[i][j], 0, 0, 0);
  }

  const int cn = lane & 15, cq = (lane >> 4) * 4;
#pragma unroll
  for (int i = 0; i < 4; ++i)
#pragma unroll
    for (int j = 0; j < 4; ++j)
#pragma unroll
      for (int r = 0; r < 4; ++r) {
        const int m = m0 + wm + i * 16 + cq + r;
        const int n = n0 + wn + j * 16 + cn;
        float v = acc[i][j][r];
        if (flags & FLAG_ACC) v += Cf[(size_t)m * N + n];
        if (bias) v += bias[n];
        if (flags & FLAG_BF) Cb[(size_t)m * N + n] = __float2bfloat16(v);
        else                 Cf[(size_t)m * N + n] = v;
      }
}

// ---------------- fused split-bf16 triple GEMM --------------------------------
// C = AH@BH^T + AL@BH^T + AH@BL^T  (effective-fp32 product), one staging pass.

__global__ __launch_bounds__(256) void gemm_bt3(
    const short* __restrict__ AH, const short* __restrict__ AL,
    const short* __restrict__ BH, const short* __restrict__ BL,
    float* __restrict__ Cf, int M, int N, int K)
{
  __shared__ __align__(16) short AsH[128 * 32];
  __shared__ __align__(16) short AsL[128 * 32];
  __shared__ __align__(16) short BsH[128 * 32];
  __shared__ __align__(16) short BsL[128 * 32];
  const int tid = threadIdx.x, lane = tid & 63, w = tid >> 6;
  const int m0 = blockIdx.y * 128, n0 = blockIdx.x * 128;
  const int wm = (w >> 1) * 64, wn = (w & 1) * 64;
  const int srow = lane >> 2, scol = (lane & 3) * 8;
  f32x4 zero = {0.f, 0.f, 0.f, 0.f};
  f32x4 acc[4][4];
#pragma unroll
  for (int i = 0; i < 4; ++i)
#pragma unroll
    for (int j = 0; j < 4; ++j) acc[i][j] = zero;

  for (int k0 = 0; k0 < K; k0 += 32) {
    __syncthreads();
#pragma unroll
    for (int s = 0; s < 2; ++s) {
      const int chunk = w * 2 + s;
      const int r = chunk * 16 + srow;
      const size_t ao = (size_t)(m0 + r) * K + k0 + scol;
      const size_t bo = (size_t)(n0 + r) * K + k0 + scol;
      gld16(AH + ao, AsH + chunk * 512);
      gld16(AL + ao, AsL + chunk * 512);
      gld16(BH + bo, BsH + chunk * 512);
      gld16(BL + bo, BsL + chunk * 512);
    }
    __syncthreads();
    const int fm = lane & 15, fq = lane >> 4;
    short8 ah[4], al[4], bh[4], bl[4];
#pragma unroll
    for (int i = 0; i < 4; ++i) {
      const int off = (wm + i * 16 + fm) * 32 + fq * 8;
      ah[i] = *(const short8*)(AsH + off);
      al[i] = *(const short8*)(AsL + off);
    }
#pragma unroll
    for (int j = 0; j < 4; ++j) {
      const int off = (wn + j * 16 + fm) * 32 + fq * 8;
      bh[j] = *(const short8*)(BsH + off);
      bl[j] = *(const short8*)(BsL + off);
    }
#pragma unroll
    for (int i = 0; i < 4; ++i)
#pragma unroll
      for (int j = 0; j < 4; ++j) {
        acc[i][j] = __builtin_amdgcn_mfma_f32_16x16x32_bf16(ah[i], bh[j], acc[i][j], 0, 0, 0);
        acc[i][j] = __builtin_amdgcn_mfma_f32_16x16x32_bf16(al[i], bh[j], acc[i][j], 0, 0, 0);
        acc[i][j] = __builtin_amdgcn_mfma_f32_16x16x32_bf16(ah[i], bl[j], acc[i][j], 0, 0, 0);
      }
  }

  const int cn = lane & 15, cq = (lane >> 4) * 4;
#pragma unroll
  for (int i = 0; i < 4; ++i)
#pragma unroll
    for (int j = 0; j < 4; ++j)
#pragma unroll
      for (int r = 0; r < 4; ++r) {
        const int m = m0 + wm + i * 16 + cq + r;
        const int n = n0 + wn + j * 16 + cn;
        Cf[(size_t)m * N + n] = acc[i][j][r];
      }
}

// ---------------- per-step kernel A: attn (blocks 0-63) + gh (blocks 64-127) --

__global__ __launch_bounds__(256) void fused_attn_gh(
    const float* __restrict__ hf, const float* __restrict__ ctxW,
    const int* __restrict__ lens, float* __restrict__ attn,
    const short* __restrict__ hhi, const short* __restrict__ hlo,
    const short* __restrict__ WhH, const short* __restrict__ WhL,
    float* __restrict__ ghG)
{
  __shared__ float hs[1024];
  __shared__ float part[256];
  const int tid = threadIdx.x;
  if (blockIdx.x < 64) {
    // ---- attention scores + softmax for batch b ----
    const int b = blockIdx.x;
    const int len = lens[b];
    ((float4*)hs)[tid] = ((const float4*)(hf + b * 1024))[tid];
    __syncthreads();
    const int l = tid >> 2, q = tid & 3;
    float s = 0.f;
    if (l < len) {
      const float4* row = (const float4*)(ctxW + ((size_t)(b * 64 + l)) * 1024 + q * 256);
      const float4* hh = (const float4*)(hs + q * 256);
#pragma unroll 8
      for (int i = 0; i < 64; ++i) {
        float4 a = row[i], c = hh[i];
        s += a.x * c.x + a.y * c.y + a.z * c.z + a.w * c.w;
      }
    }
    part[tid] = s;
    __syncthreads();
    if (tid < 64) {   // exactly wave 0; tid == context position
      float sc = part[tid * 4] + part[tid * 4 + 1] + part[tid * 4 + 2] + part[tid * 4 + 3];
      if (tid >= len) sc = -1e9f;
      float m = sc;
#pragma unroll
      for (int off = 32; off > 0; off >>= 1) m = fmaxf(m, __shfl_xor(m, off));
      float e = __expf(sc - m);
      float sum = e;
#pragma unroll
      for (int off = 32; off > 0; off >>= 1) sum += __shfl_xor(sum, off);
      attn[b * 64 + tid] = e / sum;
    }
  } else {
    // ---- gh = Whh_slice @ h, split-bf16 3-pass MFMA -> ghG[j'][b] fp32 ----
    const int j0 = (blockIdx.x - 64) * 48;
    const int lane = tid & 63, w = tid >> 6;
    const int fm = lane & 15, fq = lane >> 4;
    f32x4 zero = {0.f, 0.f, 0.f, 0.f};
    f32x4 acc0 = zero, acc1 = zero, acc2 = zero;
    const short* ah  = hhi + (w * 16 + fm) * 1024 + fq * 8;   // batches w*16..+15
    const short* al  = hlo + (w * 16 + fm) * 1024 + fq * 8;
    const short* bh0 = WhH + (size_t)(j0 + 0 * 16 + fm) * 1024 + fq * 8;
    const short* bh1 = WhH + (size_t)(j0 + 1 * 16 + fm) * 1024 + fq * 8;
    const short* bh2 = WhH + (size_t)(j0 + 2 * 16 + fm) * 1024 + fq * 8;
    const short* bl0 = WhL + (size_t)(j0 + 0 * 16 + fm) * 1024 + fq * 8;
    const short* bl1 = WhL + (size_t)(j0 + 1 * 16 + fm) * 1024 + fq * 8;
    const short* bl2 = WhL + (size_t)(j0 + 2 * 16 + fm) * 1024 + fq * 8;
#pragma unroll 2
    for (int k0 = 0; k0 < 1024; k0 += 32) {
      short8 aH = *(const short8*)(ah + k0);
      short8 aL = *(const short8*)(al + k0);
      short8 b0 = *(const short8*)(bh0 + k0);
      short8 b1 = *(const short8*)(bh1 + k0);
      short8 b2 = *(const short8*)(bh2 + k0);
      short8 c0 = *(const short8*)(bl0 + k0);
      short8 c1 = *(const short8*)(bl1 + k0);
      short8 c2 = *(const short8*)(bl2 + k0);
      acc0 = __builtin_amdgcn_mfma_f32_16x16x32_bf16(aH, b0, acc0, 0, 0, 0);
      acc1 = __builtin_amdgcn_mfma_f32_16x16x32_bf16(aH, b1, acc1, 0, 0, 0);
      acc2 = __builtin_amdgcn_mfma_f32_16x16x32_bf16(aH, b2, acc2, 0, 0, 0);
      acc0 = __builtin_amdgcn_mfma_f32_16x16x32_bf16(aL, b0, acc0, 0, 0, 0);
      acc1 = __builtin_amdgcn_mfma_f32_16x16x32_bf16(aL, b1, acc1, 0, 0, 0);
      acc2 = __builtin_amdgcn_mfma_f32_16x16x32_bf16(aL, b2, acc2, 0, 0, 0);
      acc0 = __builtin_amdgcn_mfma_f32_16x16x32_bf16(aH, c0, acc0, 0, 0, 0);
      acc1 = __builtin_amdgcn_mfma_f32_16x16x32_bf16(aH, c1, acc1, 0, 0, 0);
      acc2 = __builtin_amdgcn_mfma_f32_16x16x32_bf16(aH, c2, acc2, 0, 0, 0);
    }
    // C layout: batch = w*16 + fq*4 + r, j-row = fm   -> ghG[j'][b], 16B stores
    const int mb = w * 16 + fq * 4;
    *(f32x4*)(ghG + (size_t)(j0 + 0 * 16 + fm) * 64 + mb) = acc0;
    *(f32x4*)(ghG + (size_t)(j0 + 1 * 16 + fm) * 64 + mb) = acc1;
    *(f32x4*)(ghG + (size_t)(j0 + 2 * 16 + fm) * 64 + mb) = acc2;
  }
}

// ---------------- per-step kernel B: gates ------------------------------------
// grid 256 = (jc 0..63) x (bc 0..3). Block: 16 units (48 j') x 16 batches.
// Compacted attention list per batch (len-skip + wl<1e-8 skip), fp32 ctxWc.

__global__ __launch_bounds__(256) void gate_kernel(
    const float* __restrict__ attn, const int* __restrict__ lens,
    const float* __restrict__ ghG, const float* __restrict__ ctxWc,
    const __hip_bfloat16* __restrict__ gxe, const float* __restrict__ bhhp,
    float* __restrict__ hf, short* __restrict__ hhi, short* __restrict__ hlo,
    float* __restrict__ out, int t)
{
  const int jc = blockIdx.x & 63, bc = blockIdx.x >> 6;
  const int j0 = jc * 48, b0 = bc * 16;
  __shared__ float ghs[48 * 17];      // [j_local][bb], stride 17 (bank spread)
  __shared__ float wv[16][64];
  __shared__ short lidx[16][64];
  __shared__ int   cnt[16];
  const int tid = threadIdx.x;
  if (tid < 16) cnt[tid] = 0;
  for (int i = tid; i < 768; i += 256) {
    const int row = i >> 4, col = i & 15;
    ghs[row * 17 + col] = ghG[(size_t)(j0 + row) * 64 + b0 + col];
  }
  __syncthreads();
  {
    const int bb = tid >> 4, l4 = (tid & 15) * 4;
    const int b = b0 + bb, len = lens[b];
#pragma unroll
    for (int k = 0; k < 4; ++k) {
      const int l = l4 + k;
      const float wl = attn[b * 64 + l];
      if (l < len && wl >= 1e-8f) {
        const int pos = atomicAdd(&cnt[bb], 1);
        lidx[bb][pos] = (short)l;
        wv[bb][pos] = wl;
      }
    }
  }
  __syncthreads();

  const int bb = tid >> 4, jg = tid & 15;
  const int b = b0 + bb;
  const int n = cnt[bb];
  float g0 = 0.f, g1 = 0.f, g2 = 0.f;
  const float* base = ctxWc + (size_t)(b * 64) * 3072 + j0 + jg * 3;
  int i = 0;
  for (; i + 1 < n; i += 2) {
    const float wa = wv[bb][i], wb = wv[bb][i + 1];
    const float* pa = base + (size_t)lidx[bb][i] * 3072;
    const float* pb = base + (size_t)lidx[bb][i + 1] * 3072;
    const float a0 = pa[0], a1 = pa[1], a2 = pa[2];
    const float c0 = pb[0], c1 = pb[1], c2 = pb[2];
    g0 += wa * a0 + wb * c0;
    g1 += wa * a1 + wb * c1;
    g2 += wa * a2 + wb * c2;
  }
  if (i < n) {
    const float wa = wv[bb][i];
    const float* pa = base + (size_t)lidx[bb][i] * 3072;
    g0 += wa * pa[0]; g1 += wa * pa[1]; g2 += wa * pa[2];
  }

  const int jp = j0 + jg * 3;
  const __hip_bfloat16* ge = gxe + (size_t)(b * 64 + t) * 3072 + jp;
  const float gxr = g0 + __bfloat162float(ge[0]);
  const float gxz = g1 + __bfloat162float(ge[1]);
  const float gxn = g2 + __bfloat162float(ge[2]);
  const float ghr = ghs[(jg * 3 + 0) * 17 + bb] + bhhp[jp + 0];
  const float ghz = ghs[(jg * 3 + 1) * 17 + bb] + bhhp[jp + 1];
  const float ghn = ghs[(jg * 3 + 2) * 17 + bb] + bhhp[jp + 2];
  const float rr = 1.f / (1.f + __expf(-(gxr + ghr)));
  const float zz = 1.f / (1.f + __expf(-(gxz + ghz)));
  const float nn = tanhf(gxn + rr * ghn);
  const int u = jc * 16 + jg;
  const float hold = hf[b * 1024 + u];
  const float hn = (1.f - zz) * nn + zz * hold;
  out[(size_t)(b * 64 + t) * 1024 + u] = hn;
  hf[b * 1024 + u] = hn;
  __hip_bfloat16 hh = __float2bfloat16(hn);
  hhi[b * 1024 + u] = *reinterpret_cast<short*>(&hh);
  __hip_bfloat16 hl = __float2bfloat16(hn - __bfloat162float(hh));
  hlo[b * 1024 + u] = *reinterpret_cast<short*>(&hl);
  if (t == 63) out[(size_t)64 * 64 * 1024 + b * 1024 + u] = hn;
}

// ---------------- launcher ----------------

extern "C" void kernel_launch(void* const* d_in, const int* in_sizes, int n_in,
                              void* d_out, int out_size, void* d_ws, size_t ws_size,
                              hipStream_t stream)
{
  const int*   tgt  = (const int*)  d_in[0];
  const float* ctx  = (const float*)d_in[1];
  const float* h0   = (const float*)d_in[2];
  const int*   lens = (const int*)  d_in[3];
  const float* embt = (const float*)d_in[4];
  const float* Wa   = (const float*)d_in[5];
  const float* Wih  = (const float*)d_in[6];
  const float* Whh  = (const float*)d_in[7];
  const float* bih  = (const float*)d_in[8];
  const float* bhh  = (const float*)d_in[9];
  float* out = (float*)d_out;

  char* p = (char*)d_ws;
  auto take = [&](size_t bytes) {
    char* q = p;
    p += (bytes + 255) & ~(size_t)255;
    return q;
  };
  short* ctx_hi = (short*)take((size_t)8388608 * 2);
  short* ctx_lo = (short*)take((size_t)8388608 * 2);
  short* Wa_hi  = (short*)take((size_t)2097152 * 2);
  short* Wa_lo  = (short*)take((size_t)2097152 * 2);
  short* WcH    = (short*)take((size_t)3072 * 2048 * 2);
  short* WcL    = (short*)take((size_t)3072 * 2048 * 2);
  short* We_p   = (short*)take((size_t)3072 * 512 * 2);
  short* WhH    = (short*)take((size_t)3072 * 1024 * 2);
  short* WhL    = (short*)take((size_t)3072 * 1024 * 2);
  float* bih_p  = (float*)take(3072 * 4);
  float* bhh_p  = (float*)take(3072 * 4);
  short* emb_bf = (short*)take((size_t)4096 * 512 * 2);
  float* ctxW   = (float*)take((size_t)4096 * 1024 * 4);
  float* ctxWc  = (float*)take((size_t)4096 * 3072 * 4);
  short* gxe    = (short*)take((size_t)4096 * 3072 * 2);
  float* hf     = (float*)take((size_t)65536 * 4);
  short* hhi    = (short*)take((size_t)65536 * 2);
  short* hlo    = (short*)take((size_t)65536 * 2);
  float* attn   = (float*)take((size_t)4096 * 4);
  float* ghG    = (float*)take((size_t)3072 * 64 * 4);

  // prologue: conversions
  split_bf16_kernel<<<2048, 256, 0, stream>>>(ctx, (__hip_bfloat16*)ctx_hi,
                                              (__hip_bfloat16*)ctx_lo, 8388608);
  split_bf16_kernel<<<1024, 256, 0, stream>>>(Wa, (__hip_bfloat16*)Wa_hi,
                                              (__hip_bfloat16*)Wa_lo, 2097152);
  prep_weights<<<3072, 256, 0, stream>>>(Wih, Whh, bih, bhh,
      (__hip_bfloat16*)WcH, (__hip_bfloat16*)WcL, (__hip_bfloat16*)We_p,
      (__hip_bfloat16*)WhH, (__hip_bfloat16*)WhL, bih_p, bhh_p);
  emb_gather<<<4096, 256, 0, stream>>>(tgt, embt, (__hip_bfloat16*)emb_bf);
  h0_init<<<256, 256, 0, stream>>>(h0, hf, (__hip_bfloat16*)hhi,
                                   (__hip_bfloat16*)hlo);

  // ctxW = ctx @ Wa^T   (split-bf16 fused 3-product, fp32 out)
  gemm_bt3<<<dim3(8, 32), 256, 0, stream>>>(ctx_hi, ctx_lo, Wa_hi, Wa_lo,
                                            ctxW, 4096, 1024, 2048);
  // ctxWc = ctx @ Wc_perm^T (split-bf16 fused 3-product, fp32 out)
  gemm_bt3<<<dim3(24, 32), 256, 0, stream>>>(ctx_hi, ctx_lo, WcH, WcL,
                                             ctxWc, 4096, 3072, 2048);
  // gxe = emb @ We_perm^T + b_ih (bf16 out; |gxe| ~ 3e-3, rounding negligible)
  gemm_bt<<<dim3(24, 32), 256, 0, stream>>>(emb_bf, We_p, nullptr,
                                            (__hip_bfloat16*)gxe, bih_p,
                                            4096, 3072, 512, FLAG_BF);

  // sequential recurrence: 2 launches per step
  for (int t = 0; t < 64; ++t) {
    fused_attn_gh<<<128, 256, 0, stream>>>(hf, ctxW, lens, attn,
                                           hhi, hlo, WhH, WhL, ghG);
    gate_kernel<<<256, 256, 0, stream>>>(attn, lens, ghG, ctxWc, 
        (const __hip_bfloat16*)gxe, bhh_p, hf, hhi, hlo, out, t);
  }
}